// Round 9
// baseline (165.255 us; speedup 1.0000x reference)
//
#include <hip/hip_runtime.h>

#define NN    100000
#define NE    1600000
#define D     128
#define P     32                 // edge slices
#define BINS  8                  // node bins
#define BSZ   12512              // nodes per bin (50 KB LDS); BINS*BSZ = 100096 >= NN
#define NNP   (BINS * BSZ)       // padded node stride (100096)
#define NNP4  (NNP / 4)          // 25024
#define SL4   (NE / 4 / P)       // int4 edges per slice = 12500 (exact)
#define RB    391                // red2node blocks: 391*64 float4 == NNP4 exactly

// XCD swizzle: blocks scanning the same edge slice s land on one XCD (blk%8 == s%8),
// so each 600 KB slice is HBM-fetched once and L2-served to the other bin-blocks.
__device__ __forceinline__ void decode(int blk, int& b, int& s) {
    int x = blk & 7, y = blk >> 3;     // y in [0,32)
    s = (y & 3) * 8 + x;               // slice  [0,32)
    b = y >> 2;                        // bin    [0,8)
}

// ---- scatter 1: degree partials pA[s][v] = sum_{col=v, e in slice s} w[e] ----
__global__ __launch_bounds__(1024) void k_scat1(const int4* __restrict__ col4,
                                                const float4* __restrict__ w4,
                                                float* __restrict__ pA) {
    __shared__ float bin[BSZ];         // 50 KB -> 2 blocks/CU (32 waves)
    int b, s; decode(blockIdx.x, b, s);
    float4* bin4 = (float4*)bin;
    for (int i = threadIdx.x; i < BSZ / 4; i += 1024) bin4[i] = make_float4(0, 0, 0, 0);
    __syncthreads();
    const int lo = b * BSZ;
    const int e1 = (s + 1) * SL4;
    for (int e = s * SL4 + threadIdx.x; e < e1; e += 1024) {
        int4 k = col4[e];
        float4 v = w4[e];
        int r0 = k.x - lo, r1 = k.y - lo, r2 = k.z - lo, r3 = k.w - lo;
        if ((unsigned)r0 < (unsigned)BSZ) atomicAdd(&bin[r0], v.x);
        if ((unsigned)r1 < (unsigned)BSZ) atomicAdd(&bin[r1], v.y);
        if ((unsigned)r2 < (unsigned)BSZ) atomicAdd(&bin[r2], v.z);
        if ((unsigned)r3 < (unsigned)BSZ) atomicAdd(&bin[r3], v.w);
    }
    __syncthreads();
    float4* dst = (float4*)(pA + (size_t)s * NNP + lo);
    for (int i = threadIdx.x; i < BSZ / 4; i += 1024) dst[i] = bin4[i];
}

// ---- reduce 1: dinv = rsqrt(1 + sum_s pA[s][v]); block 0: s1 = colsum(W1), accg = 0 ----
__global__ __launch_bounds__(256) void k_red1(const float* __restrict__ pA,
                                              const float* __restrict__ W1,
                                              float* __restrict__ dinv,
                                              float* __restrict__ s1,
                                              float* __restrict__ accg) {
    int v4 = blockIdx.x * 256 + threadIdx.x;
    if (v4 < NNP4) {
        float4 a = make_float4(1.f, 1.f, 1.f, 1.f);   // self-loop weight
        #pragma unroll 8
        for (int ss = 0; ss < P; ++ss) {
            float4 p = ((const float4*)(pA + (size_t)ss * NNP))[v4];
            a.x += p.x; a.y += p.y; a.z += p.z; a.w += p.w;
        }
        float4 r;
        r.x = rsqrtf(a.x); r.y = rsqrtf(a.y); r.z = rsqrtf(a.z); r.w = rsqrtf(a.w);
        ((float4*)dinv)[v4] = r;
    }
    if (blockIdx.x == 0 && threadIdx.x < D) {
        int j = threadIdx.x;
        float sv = 0.f;
        for (int r = 0; r < D; ++r) sv += W1[r * D + j];
        s1[j] = sv;
        accg[j] = 0.f;                 // ws is re-poisoned before every call
    }
}

// ---- scatter 2, role-split for occupancy (50 KB LDS -> 2 blocks/CU = 32 waves):
//  role 0: pS[s][v] = sum_{col=v} w*dinv[row]
//  role 1: pU[s][v] = sum_{row=v} w*dinv[col]
//  dinv gathers predicated under the bin test (8x fewer gather requests than r0).
//  role*256 % 8 == 0 keeps the blk%8 == s%8 XCD-swizzle invariant. ----
__global__ __launch_bounds__(1024) void k_scat2(const int4* __restrict__ col4,
                                                const int4* __restrict__ row4,
                                                const float4* __restrict__ w4,
                                                const float* __restrict__ dinv,
                                                float* __restrict__ pS,
                                                float* __restrict__ pU) {
    __shared__ float bin[BSZ];         // 50 KB
    const int role = blockIdx.x >> 8;  // 0: S, 1: U
    int b, s; decode(blockIdx.x & 255, b, s);
    float4* bin4 = (float4*)bin;
    for (int i = threadIdx.x; i < BSZ / 4; i += 1024) bin4[i] = make_float4(0, 0, 0, 0);
    __syncthreads();
    const int4* idx4 = role ? row4 : col4;   // scatter index stream
    const int4* oth4 = role ? col4 : row4;   // gather index stream
    const int lo = b * BSZ;
    const int e1 = (s + 1) * SL4;
    for (int e = s * SL4 + threadIdx.x; e < e1; e += 1024) {
        int4 a = idx4[e];
        int4 o = oth4[e];
        float4 w = w4[e];
        int i0 = a.x - lo, i1 = a.y - lo, i2 = a.z - lo, i3 = a.w - lo;
        if ((unsigned)i0 < (unsigned)BSZ) atomicAdd(&bin[i0], w.x * dinv[o.x]);
        if ((unsigned)i1 < (unsigned)BSZ) atomicAdd(&bin[i1], w.y * dinv[o.y]);
        if ((unsigned)i2 < (unsigned)BSZ) atomicAdd(&bin[i2], w.z * dinv[o.z]);
        if ((unsigned)i3 < (unsigned)BSZ) atomicAdd(&bin[i3], w.w * dinv[o.w]);
    }
    __syncthreads();
    float* dstP = role ? pU : pS;
    float4* dst = (float4*)(dstP + (size_t)s * NNP + lo);
    for (int i = threadIdx.x; i < BSZ / 4; i += 1024) dst[i] = bin4[i];
}

// ---- reduce 2 + node-dot (c/wgt never hit HBM):
//  c = dinv*(S+dinv), wgt = dinv*(U+dinv);  accg[j] += sum_v wgt*relu(c*s1[j]+b1[j])
__global__ __launch_bounds__(256) void k_red2node(const float* __restrict__ pS,
                                                  const float* __restrict__ pU,
                                                  const float* __restrict__ dinv,
                                                  const float* __restrict__ s1,
                                                  const float* __restrict__ b1,
                                                  float* __restrict__ accg) {
    __shared__ float4 sS[256], sU[256];       // 4-way slice-split partials
    __shared__ float4 ldsC[64], ldsW[64];     // 256 nodes per block
    __shared__ float red[D];
    const int t = threadIdx.x;
    const int q = t & 63;                     // float4 index within block chunk
    const int grp = t >> 6;                   // 0..3: slice sub-range
    const int v4 = blockIdx.x * 64 + q;       // 391*64 == NNP4 exactly

    // phase A: all 256 threads reduce 8 slices each of S and U
    float4 S = make_float4(0, 0, 0, 0), U = make_float4(0, 0, 0, 0);
    #pragma unroll
    for (int k = 0; k < P / 4; ++k) {
        int ss = grp * (P / 4) + k;
        float4 a = ((const float4*)(pS + (size_t)ss * NNP))[v4];
        float4 u = ((const float4*)(pU + (size_t)ss * NNP))[v4];
        S.x += a.x; S.y += a.y; S.z += a.z; S.w += a.w;
        U.x += u.x; U.y += u.y; U.z += u.z; U.w += u.w;
    }
    sS[t] = S; sU[t] = U;
    __syncthreads();
    if (t < 64) {
        float4 S0 = sS[t], S1 = sS[64 + t], S2 = sS[128 + t], S3 = sS[192 + t];
        float4 U0 = sU[t], U1 = sU[64 + t], U2 = sU[128 + t], U3 = sU[192 + t];
        float4 Sa, Ua;
        Sa.x = S0.x + S1.x + S2.x + S3.x; Sa.y = S0.y + S1.y + S2.y + S3.y;
        Sa.z = S0.z + S1.z + S2.z + S3.z; Sa.w = S0.w + S1.w + S2.w + S3.w;
        Ua.x = U0.x + U1.x + U2.x + U3.x; Ua.y = U0.y + U1.y + U2.y + U3.y;
        Ua.z = U0.z + U1.z + U2.z + U3.z; Ua.w = U0.w + U1.w + U2.w + U3.w;
        float4 dv = ((const float4*)dinv)[v4];
        float4 cc, ww;
        cc.x = dv.x * (Sa.x + dv.x); cc.y = dv.y * (Sa.y + dv.y);
        cc.z = dv.z * (Sa.z + dv.z); cc.w = dv.w * (Sa.w + dv.w);
        ww.x = dv.x * (Ua.x + dv.x); ww.y = dv.y * (Ua.y + dv.y);
        ww.z = dv.z * (Ua.z + dv.z); ww.w = dv.w * (Ua.w + dv.w);
        int v0 = v4 * 4;                      // mask padded fake nodes (v >= NN)
        if (v0 + 0 >= NN) ww.x = 0.f;
        if (v0 + 1 >= NN) ww.y = 0.f;
        if (v0 + 2 >= NN) ww.z = 0.f;
        if (v0 + 3 >= NN) ww.w = 0.f;
        ldsC[t] = cc; ldsW[t] = ww;
    }
    __syncthreads();

    // phase B: node-dot. 2 j-groups of 128 lanes; group g scans 32 float4 node-packs.
    const int j = t & (D - 1), g = t >> 7;
    const float sj = s1[j], bj = b1[j];
    float acc = 0.f;
    #pragma unroll
    for (int k = 0; k < 32; ++k) {
        float4 c4 = ldsC[g * 32 + k];         // wave-uniform LDS broadcast
        float4 w4 = ldsW[g * 32 + k];
        acc += w4.x * fmaxf(fmaf(c4.x, sj, bj), 0.f);
        acc += w4.y * fmaxf(fmaf(c4.y, sj, bj), 0.f);
        acc += w4.z * fmaxf(fmaf(c4.z, sj, bj), 0.f);
        acc += w4.w * fmaxf(fmaf(c4.w, sj, bj), 0.f);
    }
    if (g) red[j] = acc;
    __syncthreads();
    if (!g) atomicAdd(&accg[j], acc + red[j]);   // 128 atomics/block, 391 blocks
}

// ---- gemv: out[k] = (1/N) * sum_j accg[j]*W2[j][k] + b2[k] ----
__global__ __launch_bounds__(256) void k_gemv(const float* __restrict__ accg,
                                              const float* __restrict__ W2,
                                              const float* __restrict__ b2,
                                              float* __restrict__ out) {
    __shared__ float a[D], r2[D];
    int t = threadIdx.x, k = t & (D - 1), g = t >> 7;
    if (t < D) a[t] = accg[t];
    __syncthreads();
    float o = 0.f;
    int j0 = g * 64;
    #pragma unroll 16
    for (int j = j0; j < j0 + 64; ++j) o = fmaf(a[j], W2[j * D + k], o);
    if (g) r2[k] = o;
    __syncthreads();
    if (!g) out[k] = (o + r2[k]) * (1.0f / (float)NN) + b2[k];
}

extern "C" void kernel_launch(void* const* d_in, const int* in_sizes, int n_in,
                              void* d_out, int out_size, void* d_ws, size_t ws_size,
                              hipStream_t stream) {
    // inputs: 0=x (unused; ref overwrites with ones), 1=edge_index [2,E] int,
    //         2=edge_attr [E] f32, 3=W1, 4=b1, 5=W2, 6=b2 (all f32)
    const int* ei    = (const int*)d_in[1];
    const int4* row4 = (const int4*)ei;
    const int4* col4 = (const int4*)(ei + NE);
    const float4* w4 = (const float4*)d_in[2];
    const float* W1 = (const float*)d_in[3];
    const float* b1 = (const float*)d_in[4];
    const float* W2 = (const float*)d_in[5];
    const float* b2 = (const float*)d_in[6];
    float* out = (float*)d_out;

    float* ws   = (float*)d_ws;
    float* pA   = ws;                        // [P*NNP] deg partials, then S partials
    float* pB   = pA + (size_t)P * NNP;      // [P*NNP] U partials
    float* dinv = pB + (size_t)P * NNP;      // [NNP]
    float* s1   = dinv + NNP;                // [D]
    float* accg = s1 + D;                    // [D]
    // total ~26 MB << ws_size; every array fully written before read -> no memset

    k_scat1   <<<BINS * P, 1024, 0, stream>>>(col4, w4, pA);
    k_red1    <<<(NNP4 + 255) / 256, 256, 0, stream>>>(pA, W1, dinv, s1, accg);
    k_scat2   <<<2 * BINS * P, 1024, 0, stream>>>(col4, row4, w4, dinv, pA, pB);
    k_red2node<<<RB, 256, 0, stream>>>(pA, pB, dinv, s1, b1, accg);
    k_gemv    <<<1, 256, 0, stream>>>(accg, W2, b2, out);
}